// Round 1
// baseline (602.471 us; speedup 1.0000x reference)
//
#include <hip/hip_runtime.h>
#include <math.h>

#define N_NODES 50000
#define N_EDGES 800000
#define NEG 0.2f

// ---------------- CSR build ----------------

__global__ void zero_kernel(int* a, int n) {
    int i = blockIdx.x * blockDim.x + threadIdx.x;
    if (i < n) a[i] = 0;
}

__global__ void count_kernel(const int* __restrict__ dst, int* cnt, int E) {
    int i = blockIdx.x * blockDim.x + threadIdx.x;
    if (i < E) atomicAdd(&cnt[dst[i]], 1);
}

// single-block exclusive scan, 1024 threads, chunked Hillis-Steele
__global__ void scan_kernel(const int* __restrict__ cnt, int* rowptr, int n) {
    __shared__ int sh[1024];
    __shared__ int carry, chunk_total;
    if (threadIdx.x == 0) carry = 0;
    __syncthreads();
    for (int base = 0; base < n; base += 1024) {
        int i = base + (int)threadIdx.x;
        int v = (i < n) ? cnt[i] : 0;
        sh[threadIdx.x] = v;
        __syncthreads();
        for (int off = 1; off < 1024; off <<= 1) {
            int t = (threadIdx.x >= off) ? sh[threadIdx.x - off] : 0;
            __syncthreads();
            sh[threadIdx.x] += t;
            __syncthreads();
        }
        int incl = sh[threadIdx.x];
        if (i < n) rowptr[i] = carry + incl - v;  // exclusive
        if (threadIdx.x == 1023) chunk_total = incl;
        __syncthreads();
        if (threadIdx.x == 0) carry += chunk_total;
        __syncthreads();
    }
    if (threadIdx.x == 0) rowptr[n] = carry;
}

__global__ void fill_kernel(const int* __restrict__ src, const int* __restrict__ dst,
                            const int* __restrict__ rowptr, int* fillc, int* col, int E) {
    int i = blockIdx.x * blockDim.x + threadIdx.x;
    if (i < E) {
        int d = dst[i];
        int pos = rowptr[d] + atomicAdd(&fillc[d], 1);
        col[pos] = src[i];
    }
}

// ---------------- GEMM: A[rows,K] @ W[K,192] -> out[rows,192] ----------------
// block = 192 threads (3 waves), 8 rows per block; x-tile in LDS, W from L2.
template <int K>
__global__ void gemm_kernel(const float* __restrict__ A, const float* __restrict__ W,
                            float* __restrict__ out, int rows) {
    __shared__ float xs[8][K];
    int row0 = blockIdx.x * 8;
    int tid = threadIdx.x;
    for (int idx = tid; idx < 8 * K; idx += 192) {
        int r = idx / K, k = idx % K;
        int rr = row0 + r;
        xs[r][k] = (rr < rows) ? A[rr * K + k] : 0.f;
    }
    __syncthreads();
    float acc[8] = {0, 0, 0, 0, 0, 0, 0, 0};
    int m = tid;  // 0..191
    for (int k = 0; k < K; ++k) {
        float w = W[k * 192 + m];
#pragma unroll
        for (int r = 0; r < 8; ++r) acc[r] += xs[r][k] * w;
    }
    for (int r = 0; r < 8; ++r) {
        int rr = row0 + r;
        if (rr < rows) out[rr * 192 + m] = acc[r];
    }
}

// ---------------- alpha dots: as[n,h] = h[n,h,:]·att_src[h,:] ----------------
__global__ void alpha_kernel(const float* __restrict__ h, const float* __restrict__ att_src,
                             const float* __restrict__ att_dst, float* __restrict__ as_,
                             float* __restrict__ ad_, int n) {
    int wid = (int)((blockIdx.x * blockDim.x + threadIdx.x) >> 6);
    int lane = threadIdx.x & 63;
    if (wid >= n) return;
#pragma unroll
    for (int hh = 0; hh < 3; ++hh) {
        float v = h[wid * 192 + hh * 64 + lane];
        float s = v * att_src[hh * 64 + lane];
        float d = v * att_dst[hh * 64 + lane];
        for (int off = 32; off; off >>= 1) {
            s += __shfl_xor(s, off);
            d += __shfl_xor(d, off);
        }
        if (lane == 0) {
            as_[wid * 3 + hh] = s;
            ad_[wid * 3 + hh] = d;
        }
    }
}

// ---------------- per-node softmax aggregation, one wave per node ----------------
template <bool RELU>
__global__ void aggregate_kernel(const float* __restrict__ h, const float* __restrict__ as_,
                                 const float* __restrict__ ad_, const float* __restrict__ bias,
                                 const int* __restrict__ rowptr, const int* __restrict__ col,
                                 float* __restrict__ out, int n) {
    int wid = (int)((blockIdx.x * blockDim.x + threadIdx.x) >> 6);
    int lane = threadIdx.x & 63;
    if (wid >= n) return;
    int d = wid;
    int r0 = rowptr[d], r1 = rowptr[d + 1];

    float adh[3], eself[3];
#pragma unroll
    for (int hh = 0; hh < 3; ++hh) {
        adh[hh] = ad_[d * 3 + hh];
        float v = as_[d * 3 + hh] + adh[hh];
        eself[hh] = v > 0.f ? v : NEG * v;
    }

    // phase A1: per-head max over incoming edges (+ self loop)
    float lm[3] = {-1e30f, -1e30f, -1e30f};
    for (int j = r0 + lane; j < r1; j += 64) {
        int s = col[j];
#pragma unroll
        for (int hh = 0; hh < 3; ++hh) {
            float v = as_[s * 3 + hh] + adh[hh];
            v = v > 0.f ? v : NEG * v;
            lm[hh] = fmaxf(lm[hh], v);
        }
    }
#pragma unroll
    for (int hh = 0; hh < 3; ++hh) {
        for (int off = 32; off; off >>= 1) lm[hh] = fmaxf(lm[hh], __shfl_xor(lm[hh], off));
        lm[hh] = fmaxf(lm[hh], eself[hh]);
    }

    // phase A2: per-head sum of exp
    float ls[3] = {0.f, 0.f, 0.f};
    for (int j = r0 + lane; j < r1; j += 64) {
        int s = col[j];
#pragma unroll
        for (int hh = 0; hh < 3; ++hh) {
            float v = as_[s * 3 + hh] + adh[hh];
            v = v > 0.f ? v : NEG * v;
            ls[hh] += __expf(v - lm[hh]);
        }
    }
    float den[3];
#pragma unroll
    for (int hh = 0; hh < 3; ++hh) {
        for (int off = 32; off; off >>= 1) ls[hh] += __shfl_xor(ls[hh], off);
        den[hh] = ls[hh] + __expf(eself[hh] - lm[hh]) + 1e-16f;
    }

    // phase B: weighted accumulation; lane = channel
    float acc[3];
#pragma unroll
    for (int hh = 0; hh < 3; ++hh)
        acc[hh] = __expf(eself[hh] - lm[hh]) * h[d * 192 + hh * 64 + lane];
    for (int j = r0; j < r1; ++j) {
        int s = col[j];
#pragma unroll
        for (int hh = 0; hh < 3; ++hh) {
            float v = as_[s * 3 + hh] + adh[hh];
            v = v > 0.f ? v : NEG * v;
            float w = __expf(v - lm[hh]);
            acc[hh] += w * h[s * 192 + hh * 64 + lane];
        }
    }
    float o = (acc[0] / den[0] + acc[1] / den[1] + acc[2] / den[2]) * (1.f / 3.f) + bias[lane];
    if (RELU) o = fmaxf(o, 0.f);
    out[d * 64 + lane] = o;
}

extern "C" void kernel_launch(void* const* d_in, const int* in_sizes, int n_in,
                              void* d_out, int out_size, void* d_ws, size_t ws_size,
                              hipStream_t stream) {
    const float* x = (const float*)d_in[0];       // [N,128]
    const int* ei = (const int*)d_in[1];          // [2,E]
    const float* W1 = (const float*)d_in[2];      // [128,192]
    const float* att_s1 = (const float*)d_in[3];  // [3,64]
    const float* att_d1 = (const float*)d_in[4];
    const float* b1 = (const float*)d_in[5];      // [64]
    const float* W2 = (const float*)d_in[6];      // [64,192]
    const float* att_s2 = (const float*)d_in[7];
    const float* att_d2 = (const float*)d_in[8];
    const float* b2 = (const float*)d_in[9];
    const int* src = ei;
    const int* dst = ei + N_EDGES;

    float* h = (float*)d_ws;                // N*192
    float* as_ = h + N_NODES * 192;         // N*3
    float* ad_ = as_ + N_NODES * 3;         // N*3
    float* out1 = ad_ + N_NODES * 3;        // N*64
    int* cnt = (int*)(out1 + N_NODES * 64); // N
    int* fillc = cnt + N_NODES;             // N
    int* rowptr = fillc + N_NODES;          // N+1
    int* col = rowptr + N_NODES + 1;        // E

    float* outf = (float*)d_out;

    // CSR build (shared by both layers)
    zero_kernel<<<(2 * N_NODES + 255) / 256, 256, 0, stream>>>(cnt, 2 * N_NODES);
    count_kernel<<<(N_EDGES + 255) / 256, 256, 0, stream>>>(dst, cnt, N_EDGES);
    scan_kernel<<<1, 1024, 0, stream>>>(cnt, rowptr, N_NODES);
    fill_kernel<<<(N_EDGES + 255) / 256, 256, 0, stream>>>(src, dst, rowptr, fillc, col, N_EDGES);

    // layer 1
    gemm_kernel<128><<<(N_NODES + 7) / 8, 192, 0, stream>>>(x, W1, h, N_NODES);
    alpha_kernel<<<(N_NODES + 3) / 4, 256, 0, stream>>>(h, att_s1, att_d1, as_, ad_, N_NODES);
    aggregate_kernel<true><<<(N_NODES + 3) / 4, 256, 0, stream>>>(h, as_, ad_, b1, rowptr, col, out1, N_NODES);

    // layer 2
    gemm_kernel<64><<<(N_NODES + 7) / 8, 192, 0, stream>>>(out1, W2, h, N_NODES);
    alpha_kernel<<<(N_NODES + 3) / 4, 256, 0, stream>>>(h, att_s2, att_d2, as_, ad_, N_NODES);
    aggregate_kernel<false><<<(N_NODES + 3) / 4, 256, 0, stream>>>(h, as_, ad_, b2, rowptr, col, outf, N_NODES);
}

// Round 2
// 478.794 us; speedup vs baseline: 1.2583x; 1.2583x over previous
//
#include <hip/hip_runtime.h>
#include <math.h>

#define N_NODES 50000
#define N_EDGES 800000
#define NEG 0.2f

// ---------------- CSR build ----------------

__global__ void zero_kernel(int* a, int n) {
    int i = blockIdx.x * blockDim.x + threadIdx.x;
    if (i < n) a[i] = 0;
}

__global__ void count_kernel(const int* __restrict__ dst, int* cnt, int E) {
    int i = blockIdx.x * blockDim.x + threadIdx.x;
    if (i < E) atomicAdd(&cnt[dst[i]], 1);
}

// multi-block scan: per-block exclusive scan of 256 elements + block total
__global__ void scan1_kernel(const int* __restrict__ cnt, int* rowptr, int* partials, int n) {
    __shared__ int sh[256];
    int tid = threadIdx.x;
    int i = blockIdx.x * 256 + tid;
    int v = (i < n) ? cnt[i] : 0;
    sh[tid] = v;
    __syncthreads();
    for (int off = 1; off < 256; off <<= 1) {
        int t = (tid >= off) ? sh[tid - off] : 0;
        __syncthreads();
        sh[tid] += t;
        __syncthreads();
    }
    if (i < n) rowptr[i] = sh[tid] - v;  // exclusive within block
    if (tid == 255) partials[blockIdx.x] = sh[255];
}

// single block: exclusive scan of block partials (nb <= 256)
__global__ void scan2_kernel(int* partials, int nb) {
    __shared__ int sh[256];
    int tid = threadIdx.x;
    int v = (tid < nb) ? partials[tid] : 0;
    sh[tid] = v;
    __syncthreads();
    for (int off = 1; off < 256; off <<= 1) {
        int t = (tid >= off) ? sh[tid - off] : 0;
        __syncthreads();
        sh[tid] += t;
        __syncthreads();
    }
    if (tid < nb) partials[tid] = sh[tid] - v;  // exclusive
}

__global__ void scan3_kernel(int* rowptr, const int* __restrict__ partials, int n) {
    int i = blockIdx.x * blockDim.x + threadIdx.x;
    if (i < n) rowptr[i] += partials[i >> 8];
    if (i == 0) rowptr[n] = N_EDGES;
}

__global__ void fill_kernel(const int* __restrict__ src, const int* __restrict__ dst,
                            const int* __restrict__ rowptr, int* fillc, int* col, int E) {
    int i = blockIdx.x * blockDim.x + threadIdx.x;
    if (i < E) {
        int d = dst[i];
        int pos = rowptr[d] + atomicAdd(&fillc[d], 1);
        col[pos] = src[i];
    }
}

// ---------------- GEMM: A[rows,K] @ W[K,192] -> out[rows,192] ----------------
// 256 threads, 64-row x 192-col block tile, 4x12 register tile per thread.
template <int K>
__global__ __launch_bounds__(256) void gemm_kernel(const float* __restrict__ A,
                                                   const float* __restrict__ W,
                                                   float* __restrict__ out, int rows) {
    constexpr int KT = 32;
    __shared__ float xs[KT][68];   // transposed x-tile, padded to 68 (16B-aligned rows)
    __shared__ float ws[KT][192];
    int tid = threadIdx.x;
    int tx = tid & 15;       // col group: cols tx*12 .. tx*12+11
    int ty = tid >> 4;       // row group: rows ty*4 .. ty*4+3
    int row0 = blockIdx.x * 64;

    float acc[4][12];
#pragma unroll
    for (int r = 0; r < 4; ++r)
#pragma unroll
        for (int c = 0; c < 12; ++c) acc[r][c] = 0.f;

    for (int kt = 0; kt < K; kt += KT) {
        // stage x tile (transposed): xs[kk][r] = A[row0+r][kt+kk]
#pragma unroll
        for (int idx = tid; idx < 64 * KT; idx += 256) {
            int r = idx >> 5, kk = idx & 31;
            int rr = row0 + r;
            xs[kk][r] = (rr < rows) ? A[rr * K + kt + kk] : 0.f;
        }
        // stage W tile
#pragma unroll
        for (int idx = tid; idx < KT * 192; idx += 256) {
            int kk = idx / 192, c = idx - kk * 192;
            ws[kk][c] = W[(kt + kk) * 192 + c];
        }
        __syncthreads();
#pragma unroll 2
        for (int k = 0; k < KT; ++k) {
            float4 a4 = *(const float4*)&xs[k][ty * 4];
            float4 w0 = *(const float4*)&ws[k][tx * 12];
            float4 w1 = *(const float4*)&ws[k][tx * 12 + 4];
            float4 w2 = *(const float4*)&ws[k][tx * 12 + 8];
            float av[4] = {a4.x, a4.y, a4.z, a4.w};
            float wv[12] = {w0.x, w0.y, w0.z, w0.w, w1.x, w1.y, w1.z, w1.w,
                            w2.x, w2.y, w2.z, w2.w};
#pragma unroll
            for (int r = 0; r < 4; ++r)
#pragma unroll
                for (int c = 0; c < 12; ++c) acc[r][c] += av[r] * wv[c];
        }
        __syncthreads();
    }
    // store
#pragma unroll
    for (int r = 0; r < 4; ++r) {
        int rr = row0 + ty * 4 + r;
        if (rr < rows) {
            float4 o0 = {acc[r][0], acc[r][1], acc[r][2], acc[r][3]};
            float4 o1 = {acc[r][4], acc[r][5], acc[r][6], acc[r][7]};
            float4 o2 = {acc[r][8], acc[r][9], acc[r][10], acc[r][11]};
            *(float4*)&out[rr * 192 + tx * 12] = o0;
            *(float4*)&out[rr * 192 + tx * 12 + 4] = o1;
            *(float4*)&out[rr * 192 + tx * 12 + 8] = o2;
        }
    }
}

// ---------------- alpha dots: as[n,h] = h[n,h,:]·att_src[h,:] ----------------
__global__ void alpha_kernel(const float* __restrict__ h, const float* __restrict__ att_src,
                             const float* __restrict__ att_dst, float* __restrict__ as_,
                             float* __restrict__ ad_, int n) {
    int wid = (int)((blockIdx.x * blockDim.x + threadIdx.x) >> 6);
    int lane = threadIdx.x & 63;
    if (wid >= n) return;
#pragma unroll
    for (int hh = 0; hh < 3; ++hh) {
        float v = h[wid * 192 + hh * 64 + lane];
        float s = v * att_src[hh * 64 + lane];
        float d = v * att_dst[hh * 64 + lane];
        for (int off = 32; off; off >>= 1) {
            s += __shfl_xor(s, off);
            d += __shfl_xor(d, off);
        }
        if (lane == 0) {
            as_[wid * 3 + hh] = s;
            ad_[wid * 3 + hh] = d;
        }
    }
}

// ---------------- per-node online-softmax aggregation, one wave per node ----------------
template <bool RELU>
__global__ void aggregate_kernel(const float* __restrict__ h, const float* __restrict__ as_,
                                 const float* __restrict__ ad_, const float* __restrict__ bias,
                                 const int* __restrict__ rowptr, const int* __restrict__ col,
                                 float* __restrict__ out, int n) {
    int wid = (int)((blockIdx.x * blockDim.x + threadIdx.x) >> 6);
    int lane = threadIdx.x & 63;
    if (wid >= n) return;
    int d = wid;
    int r0 = rowptr[d], r1 = rowptr[d + 1];

    float adh[3], m[3], den_[3], acc[3];
#pragma unroll
    for (int hh = 0; hh < 3; ++hh) {
        adh[hh] = ad_[d * 3 + hh];
        float v = as_[d * 3 + hh] + adh[hh];
        float es = v > 0.f ? v : NEG * v;  // self-loop score
        m[hh] = es;                        // running max starts at self
        den_[hh] = 1.f;                    // exp(es - m) = 1
        acc[hh] = h[d * 192 + hh * 64 + lane];
    }

    for (int j0 = r0; j0 < r1; j0 += 64) {
        int jj = j0 + lane;
        bool act = jj < r1;
        int s = act ? col[jj] : 0;
        const float* ap = as_ + s * 3;
        float v[3], w[3];
#pragma unroll
        for (int hh = 0; hh < 3; ++hh) {
            float t = ap[hh] + adh[hh];
            t = t > 0.f ? t : NEG * t;
            v[hh] = act ? t : -1e30f;
        }
        // chunk max, online rescale, per-lane weight, chunk denom
#pragma unroll
        for (int hh = 0; hh < 3; ++hh) {
            float cm = v[hh];
            for (int off = 32; off; off >>= 1) cm = fmaxf(cm, __shfl_xor(cm, off));
            float mn = fmaxf(m[hh], cm);
            float sc = __expf(m[hh] - mn);
            m[hh] = mn;
            den_[hh] *= sc;
            acc[hh] *= sc;
            w[hh] = __expf(v[hh] - mn);  // 0 for inactive lanes
            float sw = w[hh];
            for (int off = 32; off; off >>= 1) sw += __shfl_xor(sw, off);
            den_[hh] += sw;
        }
        // serial weighted gather; broadcast (s, w) from the owning lane
        int ne = min(64, r1 - j0);
        for (int e = 0; e < ne; ++e) {
            int se = __shfl(s, e);
            float w0 = __shfl(w[0], e);
            float w1 = __shfl(w[1], e);
            float w2 = __shfl(w[2], e);
            const float* hp = h + se * 192 + lane;
            acc[0] += w0 * hp[0];
            acc[1] += w1 * hp[64];
            acc[2] += w2 * hp[128];
        }
    }
    float o = (acc[0] / (den_[0] + 1e-16f) + acc[1] / (den_[1] + 1e-16f) +
               acc[2] / (den_[2] + 1e-16f)) * (1.f / 3.f) + bias[lane];
    if (RELU) o = fmaxf(o, 0.f);
    out[d * 64 + lane] = o;
}

extern "C" void kernel_launch(void* const* d_in, const int* in_sizes, int n_in,
                              void* d_out, int out_size, void* d_ws, size_t ws_size,
                              hipStream_t stream) {
    const float* x = (const float*)d_in[0];       // [N,128]
    const int* ei = (const int*)d_in[1];          // [2,E]
    const float* W1 = (const float*)d_in[2];      // [128,192]
    const float* att_s1 = (const float*)d_in[3];  // [3,64]
    const float* att_d1 = (const float*)d_in[4];
    const float* b1 = (const float*)d_in[5];      // [64]
    const float* W2 = (const float*)d_in[6];      // [64,192]
    const float* att_s2 = (const float*)d_in[7];
    const float* att_d2 = (const float*)d_in[8];
    const float* b2 = (const float*)d_in[9];
    const int* src = ei;
    const int* dst = ei + N_EDGES;

    float* h = (float*)d_ws;                // N*192
    float* as_ = h + N_NODES * 192;         // N*3
    float* ad_ = as_ + N_NODES * 3;         // N*3
    float* out1 = ad_ + N_NODES * 3;        // N*64
    int* cnt = (int*)(out1 + N_NODES * 64); // N
    int* fillc = cnt + N_NODES;             // N
    int* rowptr = fillc + N_NODES;          // N+1
    int* col = rowptr + N_NODES + 1;        // E
    int* partials = (int*)h;                // reuse h (written only after CSR build)

    float* outf = (float*)d_out;
    const int NB = (N_NODES + 255) / 256;   // 196 scan blocks

    // CSR build (shared by both layers)
    zero_kernel<<<(2 * N_NODES + 255) / 256, 256, 0, stream>>>(cnt, 2 * N_NODES);
    count_kernel<<<(N_EDGES + 255) / 256, 256, 0, stream>>>(dst, cnt, N_EDGES);
    scan1_kernel<<<NB, 256, 0, stream>>>(cnt, rowptr, partials, N_NODES);
    scan2_kernel<<<1, 256, 0, stream>>>(partials, NB);
    scan3_kernel<<<NB, 256, 0, stream>>>(rowptr, partials, N_NODES);
    fill_kernel<<<(N_EDGES + 255) / 256, 256, 0, stream>>>(src, dst, rowptr, fillc, col, N_EDGES);

    // layer 1
    gemm_kernel<128><<<(N_NODES + 63) / 64, 256, 0, stream>>>(x, W1, h, N_NODES);
    alpha_kernel<<<(N_NODES + 3) / 4, 256, 0, stream>>>(h, att_s1, att_d1, as_, ad_, N_NODES);
    aggregate_kernel<true><<<(N_NODES + 3) / 4, 256, 0, stream>>>(h, as_, ad_, b1, rowptr, col, out1, N_NODES);

    // layer 2
    gemm_kernel<64><<<(N_NODES + 63) / 64, 256, 0, stream>>>(out1, W2, h, N_NODES);
    alpha_kernel<<<(N_NODES + 3) / 4, 256, 0, stream>>>(h, att_s2, att_d2, as_, ad_, N_NODES);
    aggregate_kernel<false><<<(N_NODES + 3) / 4, 256, 0, stream>>>(h, as_, ad_, b2, rowptr, col, outf, N_NODES);
}